// Round 1
// baseline (142.023 us; speedup 1.0000x reference)
//
#include <hip/hip_runtime.h>

#define DD 128   // feature dim D
#define HH 128   // hidden dim H
#define KK 32    // neighbors per node

// ---------------------------------------------------------------------------
// Kernel 1: y = x @ W   (f32, vector ALU — no fp32 MFMA on CDNA4)
// 32 rows per block, 256 threads; each thread computes 4 rows x 4 cols.
// x tile staged in LDS (16 KB); W streamed from global (64 KB, L1/L2 resident).
// ---------------------------------------------------------------------------
__global__ __launch_bounds__(256) void gemm_xw(const float* __restrict__ x,
                                               const float* __restrict__ W,
                                               float* __restrict__ y, int N) {
    __shared__ float sx[32 * DD];   // 16 KB
    const int t = threadIdx.x;
    const int row0 = blockIdx.x * 32;
    int rows_here = N - row0; if (rows_here > 32) rows_here = 32;

    // stage x tile: 32 rows * 32 float4 = 1024 float4, 256 threads -> 4 each
    float4* sx4 = (float4*)sx;
    const float4* x4 = (const float4*)x + (size_t)row0 * (DD / 4);
#pragma unroll
    for (int i = 0; i < 4; ++i) {
        int idx = t + i * 256;              // 0..1023 ; row = idx>>5
        if ((idx >> 5) < rows_here) sx4[idx] = x4[idx];
    }
    __syncthreads();

    const int r0 = (t >> 5) * 4;            // 0,4,...,28
    const int c4 = t & 31;                  // float4 column group
    const float4* W4 = (const float4*)W;

    float4 a0 = make_float4(0.f, 0.f, 0.f, 0.f);
    float4 a1 = a0, a2 = a0, a3 = a0;

#pragma unroll 8
    for (int k = 0; k < DD; ++k) {
        float4 w = W4[k * (HH / 4) + c4];   // 512B/row, L1/L2-hit
        float x0 = sx[(r0 + 0) * DD + k];
        float x1 = sx[(r0 + 1) * DD + k];
        float x2 = sx[(r0 + 2) * DD + k];
        float x3 = sx[(r0 + 3) * DD + k];
        a0.x = fmaf(x0, w.x, a0.x); a0.y = fmaf(x0, w.y, a0.y);
        a0.z = fmaf(x0, w.z, a0.z); a0.w = fmaf(x0, w.w, a0.w);
        a1.x = fmaf(x1, w.x, a1.x); a1.y = fmaf(x1, w.y, a1.y);
        a1.z = fmaf(x1, w.z, a1.z); a1.w = fmaf(x1, w.w, a1.w);
        a2.x = fmaf(x2, w.x, a2.x); a2.y = fmaf(x2, w.y, a2.y);
        a2.z = fmaf(x2, w.z, a2.z); a2.w = fmaf(x2, w.w, a2.w);
        a3.x = fmaf(x3, w.x, a3.x); a3.y = fmaf(x3, w.y, a3.y);
        a3.z = fmaf(x3, w.z, a3.z); a3.w = fmaf(x3, w.w, a3.w);
    }

    float4* yp = (float4*)y;
    if (r0 + 0 < rows_here) yp[(size_t)(row0 + r0 + 0) * (HH / 4) + c4] = a0;
    if (r0 + 1 < rows_here) yp[(size_t)(row0 + r0 + 1) * (HH / 4) + c4] = a1;
    if (r0 + 2 < rows_here) yp[(size_t)(row0 + r0 + 2) * (HH / 4) + c4] = a2;
    if (r0 + 3 < rows_here) yp[(size_t)(row0 + r0 + 3) * (HH / 4) + c4] = a3;
}

// ---------------------------------------------------------------------------
// Kernel 2: out[n,h] = (1/K) * sum_k relu(y[e[n,k]][h] - (y[n][h] - b[h]))
// 2 nodes per 256-thread block; 32 indices staged in LDS; fully unrolled
// gather loop -> 32 independent 512B-row gathers in flight (L2/L3-served).
// ---------------------------------------------------------------------------
__global__ __launch_bounds__(256) void edge_mean(const float* __restrict__ y,
                                                 const float* __restrict__ b,
                                                 const int* __restrict__ eidx,
                                                 float* __restrict__ out, int N) {
    __shared__ int sidx[2][KK];
    const int nl = threadIdx.x >> 7;        // 0/1: node within block
    const int h  = threadIdx.x & 127;
    const int n  = blockIdx.x * 2 + nl;

    if (threadIdx.x < 2 * KK) {
        int l = threadIdx.x >> 5, k = threadIdx.x & 31;
        int nn = blockIdx.x * 2 + l;
        sidx[l][k] = (nn < N) ? eidx[(size_t)nn * KK + k] : 0;
    }

    float c = 0.f;
    if (n < N) c = y[(size_t)n * HH + h] - b[h];
    __syncthreads();
    if (n >= N) return;

    float acc = 0.f;
#pragma unroll
    for (int k = 0; k < KK; ++k) {
        int j = sidx[nl][k];
        float v = y[(size_t)j * HH + h];
        acc += fmaxf(v - c, 0.f);
    }
    out[(size_t)n * HH + h] = acc * (1.0f / KK);
}

// ---------------------------------------------------------------------------
// Fallback (only if ws_size < N*H*4): fused direct compute, correct but slow.
// One block per node, 128 threads (thread = output channel h).
// ---------------------------------------------------------------------------
__global__ __launch_bounds__(128) void direct_conv(const float* __restrict__ x,
                                                   const float* __restrict__ W,
                                                   const float* __restrict__ b,
                                                   const int* __restrict__ eidx,
                                                   float* __restrict__ out, int N) {
    __shared__ float sxi[DD];
    __shared__ float sdiff[DD];
    __shared__ int   sidx[KK];
    const int t = threadIdx.x;
    const int n = blockIdx.x;
    if (n >= N) return;

    sxi[t] = x[(size_t)n * DD + t];
    if (t < KK) sidx[t] = eidx[(size_t)n * KK + t];
    __syncthreads();

    float acc = 0.f;
    const float bb = b[t];
    for (int k = 0; k < KK; ++k) {
        int j = sidx[k];
        sdiff[t] = x[(size_t)j * DD + t] - sxi[t];
        __syncthreads();
        float dot = bb;
#pragma unroll 8
        for (int d = 0; d < DD; ++d)
            dot = fmaf(sdiff[d], W[(size_t)d * HH + t], dot);
        acc += fmaxf(dot, 0.f);
        __syncthreads();
    }
    out[(size_t)n * HH + t] = acc * (1.0f / KK);
}

extern "C" void kernel_launch(void* const* d_in, const int* in_sizes, int n_in,
                              void* d_out, int out_size, void* d_ws, size_t ws_size,
                              hipStream_t stream) {
    const float* x    = (const float*)d_in[0];
    const float* W    = (const float*)d_in[1];
    const float* b    = (const float*)d_in[2];
    const int*   eidx = (const int*)d_in[3];
    float*       out  = (float*)d_out;
    const int N = in_sizes[0] / DD;

    const size_t need = (size_t)N * HH * sizeof(float);
    if (ws_size >= need) {
        float* y = (float*)d_ws;
        gemm_xw<<<(N + 31) / 32, 256, 0, stream>>>(x, W, y, N);
        edge_mean<<<(N + 1) / 2, 256, 0, stream>>>(y, b, eidx, out, N);
    } else {
        direct_conv<<<N, 128, 0, stream>>>(x, W, b, eidx, out, N);
    }
}

// Round 2
// 85.052 us; speedup vs baseline: 1.6698x; 1.6698x over previous
//
#include <hip/hip_runtime.h>

#define DD 128   // feature dim D
#define HH 128   // hidden dim H
#define KK 32    // neighbors per node

__device__ __forceinline__ ushort f2bf(float f) {
    unsigned u = __float_as_uint(f);
    u += 0x7fffu + ((u >> 16) & 1u);        // round-to-nearest-even
    return (ushort)(u >> 16);
}
__device__ __forceinline__ float bf2f(ushort s) {
    return __uint_as_float(((unsigned)s) << 16);
}

// ---------------------------------------------------------------------------
// Kernel 1: y_bf16 = bf16(x @ W)   (f32 vector FMA, bf16 store)
// 32 rows per block, 256 threads; each thread: 4 rows x 4 cols.
// x tile in LDS, read via float4 (ds_read_b128, broadcast across half-wave).
// ---------------------------------------------------------------------------
__global__ __launch_bounds__(256) void gemm_xw(const float* __restrict__ x,
                                               const float* __restrict__ W,
                                               ushort* __restrict__ yb, int N) {
    __shared__ float sx[32 * DD];   // 16 KB
    const int t = threadIdx.x;
    const int row0 = blockIdx.x * 32;
    int rows_here = N - row0; if (rows_here > 32) rows_here = 32;

    float4* sx4 = (float4*)sx;
    const float4* x4 = (const float4*)x + (size_t)row0 * (DD / 4);
#pragma unroll
    for (int i = 0; i < 4; ++i) {
        int idx = t + i * 256;              // 0..1023 ; row = idx>>5
        if ((idx >> 5) < rows_here) sx4[idx] = x4[idx];
    }
    __syncthreads();

    const int r0 = (t >> 5) * 4;            // 0,4,...,28
    const int c4 = t & 31;                  // float4 column group
    const float4* W4 = (const float4*)W;

    float4 a0 = make_float4(0.f, 0.f, 0.f, 0.f);
    float4 a1 = a0, a2 = a0, a3 = a0;

#pragma unroll 2
    for (int k4 = 0; k4 < DD / 4; ++k4) {
        float4 w0 = W4[(4 * k4 + 0) * (HH / 4) + c4];
        float4 w1 = W4[(4 * k4 + 1) * (HH / 4) + c4];
        float4 w2 = W4[(4 * k4 + 2) * (HH / 4) + c4];
        float4 w3 = W4[(4 * k4 + 3) * (HH / 4) + c4];
        float4 xr;
#define ROWFMA(ACC, R)                                                         \
        xr = sx4[(r0 + R) * (DD / 4) + k4];                                    \
        ACC.x = fmaf(xr.x, w0.x, ACC.x); ACC.y = fmaf(xr.x, w0.y, ACC.y);      \
        ACC.z = fmaf(xr.x, w0.z, ACC.z); ACC.w = fmaf(xr.x, w0.w, ACC.w);      \
        ACC.x = fmaf(xr.y, w1.x, ACC.x); ACC.y = fmaf(xr.y, w1.y, ACC.y);      \
        ACC.z = fmaf(xr.y, w1.z, ACC.z); ACC.w = fmaf(xr.y, w1.w, ACC.w);      \
        ACC.x = fmaf(xr.z, w2.x, ACC.x); ACC.y = fmaf(xr.z, w2.y, ACC.y);      \
        ACC.z = fmaf(xr.z, w2.z, ACC.z); ACC.w = fmaf(xr.z, w2.w, ACC.w);      \
        ACC.x = fmaf(xr.w, w3.x, ACC.x); ACC.y = fmaf(xr.w, w3.y, ACC.y);      \
        ACC.z = fmaf(xr.w, w3.z, ACC.z); ACC.w = fmaf(xr.w, w3.w, ACC.w);
        ROWFMA(a0, 0) ROWFMA(a1, 1) ROWFMA(a2, 2) ROWFMA(a3, 3)
#undef ROWFMA
    }

    ushort4* yp = (ushort4*)yb;
#define STORE(ACC, R)                                                          \
    if (r0 + R < rows_here)                                                    \
        yp[(size_t)(row0 + r0 + R) * (HH / 4) + c4] =                          \
            make_ushort4(f2bf(ACC.x), f2bf(ACC.y), f2bf(ACC.z), f2bf(ACC.w));
    STORE(a0, 0) STORE(a1, 1) STORE(a2, 2) STORE(a3, 3)
#undef STORE
}

// ---------------------------------------------------------------------------
// Kernel 2: out[n,h] = (1/K) * sum_k relu(y[e[n,k]][h] - (y[n][h] - b[h]))
// y in bf16 (256 B/row gathers). 4 nodes per 256-thread block; thread = 2
// channels (ushort2 loads). Fully unrolled -> 32 gathers in flight.
// ---------------------------------------------------------------------------
__global__ __launch_bounds__(256) void edge_mean(const ushort* __restrict__ yb,
                                                 const float* __restrict__ b,
                                                 const int* __restrict__ eidx,
                                                 float* __restrict__ out, int N) {
    __shared__ int sidx[4][KK];
    const int nl  = threadIdx.x >> 6;       // 0..3: node within block
    const int t64 = threadIdx.x & 63;       // lane within node
    const int h0  = t64 * 2;
    const int n   = blockIdx.x * 4 + nl;

    if (threadIdx.x < 4 * KK) {
        // contiguous: blockIdx.x*128 + tid over eidx
        int nn = blockIdx.x * 4 + (threadIdx.x >> 5);
        sidx[threadIdx.x >> 5][threadIdx.x & 31] =
            (nn < N) ? eidx[(size_t)nn * KK + (threadIdx.x & 31)] : 0;
    }

    float c0 = 0.f, c1 = 0.f;
    if (n < N) {
        ushort2 cv = ((const ushort2*)(yb + (size_t)n * HH))[t64];
        c0 = bf2f(cv.x) - b[h0];
        c1 = bf2f(cv.y) - b[h0 + 1];
    }
    __syncthreads();
    if (n >= N) return;

    float acc0 = 0.f, acc1 = 0.f;
#pragma unroll
    for (int k = 0; k < KK; ++k) {
        int j = sidx[nl][k];
        ushort2 v = ((const ushort2*)(yb + (size_t)j * HH))[t64];
        acc0 += fmaxf(bf2f(v.x) - c0, 0.f);
        acc1 += fmaxf(bf2f(v.y) - c1, 0.f);
    }
    ((float2*)out)[(size_t)n * (HH / 2) + t64] =
        make_float2(acc0 * (1.0f / KK), acc1 * (1.0f / KK));
}

// ---------------------------------------------------------------------------
// Fallback (only if ws_size too small): fused direct compute, correct but slow.
// ---------------------------------------------------------------------------
__global__ __launch_bounds__(128) void direct_conv(const float* __restrict__ x,
                                                   const float* __restrict__ W,
                                                   const float* __restrict__ b,
                                                   const int* __restrict__ eidx,
                                                   float* __restrict__ out, int N) {
    __shared__ float sxi[DD];
    __shared__ float sdiff[DD];
    __shared__ int   sidx[KK];
    const int t = threadIdx.x;
    const int n = blockIdx.x;
    if (n >= N) return;

    sxi[t] = x[(size_t)n * DD + t];
    if (t < KK) sidx[t] = eidx[(size_t)n * KK + t];
    __syncthreads();

    float acc = 0.f;
    const float bb = b[t];
    for (int k = 0; k < KK; ++k) {
        int j = sidx[k];
        sdiff[t] = x[(size_t)j * DD + t] - sxi[t];
        __syncthreads();
        float dot = bb;
#pragma unroll 8
        for (int d = 0; d < DD; ++d)
            dot = fmaf(sdiff[d], W[(size_t)d * HH + t], dot);
        acc += fmaxf(dot, 0.f);
        __syncthreads();
    }
    out[(size_t)n * HH + t] = acc * (1.0f / KK);
}

extern "C" void kernel_launch(void* const* d_in, const int* in_sizes, int n_in,
                              void* d_out, int out_size, void* d_ws, size_t ws_size,
                              hipStream_t stream) {
    const float* x    = (const float*)d_in[0];
    const float* W    = (const float*)d_in[1];
    const float* b    = (const float*)d_in[2];
    const int*   eidx = (const int*)d_in[3];
    float*       out  = (float*)d_out;
    const int N = in_sizes[0] / DD;

    const size_t need = (size_t)N * HH * sizeof(ushort);
    if (ws_size >= need) {
        ushort* yb = (ushort*)d_ws;
        gemm_xw<<<(N + 31) / 32, 256, 0, stream>>>(x, W, yb, N);
        edge_mean<<<(N + 3) / 4, 256, 0, stream>>>(yb, b, eidx, out, N);
    } else {
        direct_conv<<<N, 128, 0, stream>>>(x, W, b, eidx, out, N);
    }
}

// Round 3
// 76.293 us; speedup vs baseline: 1.8616x; 1.1148x over previous
//
#include <hip/hip_runtime.h>

#define DD 128   // feature dim D
#define HH 128   // hidden dim H
#define KK 32    // neighbors per node
#define TM 64    // gemm rows per block
#define LDP 136  // padded LDS row length (f16 elems): 272 B stride -> 2-way bank alias (free)

typedef _Float16 half8 __attribute__((ext_vector_type(8)));
typedef float    f32x4 __attribute__((ext_vector_type(4)));

__device__ __forceinline__ float h2f(ushort s) {
    return (float)__builtin_bit_cast(_Float16, s);
}
__device__ __forceinline__ ushort f2h(float f) {
    return __builtin_bit_cast(ushort, (_Float16)f);
}

// ---------------------------------------------------------------------------
// Kernel 1: y_f16 = f16(x @ W) via MFMA 16x16x32_f16.
// Block: 256 thr = 4 waves; tile 64 rows x 128 cols, K=128 in 4 steps.
// x-tile and W^T staged in LDS as f16 (padded rows). Each wave: 16 rows,
// 8 col-tiles, acc in 8x f32x4.
// ---------------------------------------------------------------------------
__global__ __launch_bounds__(256) void gemm_mfma(const float* __restrict__ x,
                                                 const float* __restrict__ W,
                                                 ushort* __restrict__ yb, int N) {
    __shared__ _Float16 sx[TM * LDP];   // 17408 B
    __shared__ _Float16 sw[HH * LDP];   // 34816 B  (W^T: [col][k])
    const int t = threadIdx.x;
    const int row0 = blockIdx.x * TM;
    int rows_here = N - row0; if (rows_here > TM) rows_here = TM;

    // stage x tile (64x128 f32 -> f16), coalesced float4 reads
    {
        const float4* x4 = (const float4*)x + (size_t)row0 * (DD / 4);
#pragma unroll
        for (int i = 0; i < (TM * DD / 4) / 256; ++i) {   // 8 iters
            int idx = t + i * 256;
            int r = idx >> 5;                // 32 float4 per row
            int c4 = idx & 31;
            float4 v = (r < rows_here) ? x4[idx] : make_float4(0.f, 0.f, 0.f, 0.f);
            _Float16* dst = &sx[r * LDP + c4 * 4];
            dst[0] = (_Float16)v.x; dst[1] = (_Float16)v.y;
            dst[2] = (_Float16)v.z; dst[3] = (_Float16)v.w;
        }
    }
    // stage W^T (read W[k][c] coalesced, write sw[c][k])
    {
        const float4* W4 = (const float4*)W;
#pragma unroll
        for (int i = 0; i < (DD * HH / 4) / 256; ++i) {   // 16 iters
            int idx = t + i * 256;
            int k = idx >> 5;
            int c4 = idx & 31;
            float4 v = W4[idx];
            sw[(c4 * 4 + 0) * LDP + k] = (_Float16)v.x;
            sw[(c4 * 4 + 1) * LDP + k] = (_Float16)v.y;
            sw[(c4 * 4 + 2) * LDP + k] = (_Float16)v.z;
            sw[(c4 * 4 + 3) * LDP + k] = (_Float16)v.w;
        }
    }
    __syncthreads();

    const int wid  = t >> 6;       // wave 0..3
    const int lane = t & 63;
    const int am   = lane & 15;    // row-in-tile (A) / col-in-tile (B)
    const int grp  = lane >> 4;    // k-group 0..3
    const int wrow = wid * 16;     // wave's row offset within tile

    f32x4 acc[8];
#pragma unroll
    for (int i = 0; i < 8; ++i) acc[i] = (f32x4){0.f, 0.f, 0.f, 0.f};

#pragma unroll
    for (int ks = 0; ks < 4; ++ks) {           // K step = 32
        const int k0 = ks * 32 + grp * 8;
        half8 a = *(const half8*)&sx[(wrow + am) * LDP + k0];
#pragma unroll
        for (int ct = 0; ct < 8; ++ct) {
            half8 bf = *(const half8*)&sw[(ct * 16 + am) * LDP + k0];
            acc[ct] = __builtin_amdgcn_mfma_f32_16x16x32_f16(a, bf, acc[ct], 0, 0, 0);
        }
    }

    // C/D layout: col = lane&15, row = (lane>>4)*4 + j   [guide §3, m89-verified]
#pragma unroll
    for (int ct = 0; ct < 8; ++ct) {
#pragma unroll
        for (int j = 0; j < 4; ++j) {
            int r = wrow + grp * 4 + j;
            if (r < rows_here)
                yb[(size_t)(row0 + r) * HH + ct * 16 + am] = f2h(acc[ct][j]);
        }
    }
}

// ---------------------------------------------------------------------------
// Kernel 2: out[n,h] = (1/K)*sum_k max(y[j], c) - c,  c = y[n] - b  (f16 y)
// 8 nodes per 256-thread block; half-wave (32 lanes) covers one 128-ch row
// via ushort4 (8 B/lane). Fully unrolled k-loop -> 32 gathers in flight.
// ---------------------------------------------------------------------------
__global__ __launch_bounds__(256) void edge_mean(const ushort* __restrict__ yb,
                                                 const float* __restrict__ b,
                                                 const int* __restrict__ eidx,
                                                 float* __restrict__ out, int N) {
    __shared__ int sidx[8][KK];
    const int node_l = threadIdx.x >> 5;    // 0..7
    const int l32    = threadIdx.x & 31;
    const int n      = blockIdx.x * 8 + node_l;

    // 256 indices, one per thread, perfectly coalesced
    ((int*)sidx)[threadIdx.x] =
        (n < N) ? eidx[(size_t)blockIdx.x * 8 * KK + threadIdx.x] : 0;

    float c0 = 0.f, c1 = 0.f, c2 = 0.f, c3 = 0.f;
    float4 bb = ((const float4*)b)[l32];
    if (n < N) {
        ushort4 cv = ((const ushort4*)yb)[(size_t)n * (HH / 4) + l32];
        c0 = h2f(cv.x) - bb.x;
        c1 = h2f(cv.y) - bb.y;
        c2 = h2f(cv.z) - bb.z;
        c3 = h2f(cv.w) - bb.w;
    }
    __syncthreads();
    if (n >= N) return;

    float a0 = 0.f, a1 = 0.f, a2 = 0.f, a3 = 0.f;
#pragma unroll
    for (int k = 0; k < KK; ++k) {
        int j = sidx[node_l][k];
        ushort4 v = ((const ushort4*)yb)[(size_t)j * (HH / 4) + l32];
        a0 += fmaxf(h2f(v.x), c0);
        a1 += fmaxf(h2f(v.y), c1);
        a2 += fmaxf(h2f(v.z), c2);
        a3 += fmaxf(h2f(v.w), c3);
    }
    ((float4*)out)[(size_t)n * (HH / 4) + l32] =
        make_float4(a0 * (1.0f / KK) - c0, a1 * (1.0f / KK) - c1,
                    a2 * (1.0f / KK) - c2, a3 * (1.0f / KK) - c3);
}

// ---------------------------------------------------------------------------
// Fallback (only if ws_size too small): fused direct compute, correct but slow.
// ---------------------------------------------------------------------------
__global__ __launch_bounds__(128) void direct_conv(const float* __restrict__ x,
                                                   const float* __restrict__ W,
                                                   const float* __restrict__ b,
                                                   const int* __restrict__ eidx,
                                                   float* __restrict__ out, int N) {
    __shared__ float sxi[DD];
    __shared__ float sdiff[DD];
    __shared__ int   sidx[KK];
    const int t = threadIdx.x;
    const int n = blockIdx.x;
    if (n >= N) return;

    sxi[t] = x[(size_t)n * DD + t];
    if (t < KK) sidx[t] = eidx[(size_t)n * KK + t];
    __syncthreads();

    float acc = 0.f;
    const float bb = b[t];
    for (int k = 0; k < KK; ++k) {
        int j = sidx[k];
        sdiff[t] = x[(size_t)j * DD + t] - sxi[t];
        __syncthreads();
        float dot = bb;
#pragma unroll 8
        for (int d = 0; d < DD; ++d)
            dot = fmaf(sdiff[d], W[(size_t)d * HH + t], dot);
        acc += fmaxf(dot, 0.f);
        __syncthreads();
    }
    out[(size_t)n * HH + t] = acc * (1.0f / KK);
}

extern "C" void kernel_launch(void* const* d_in, const int* in_sizes, int n_in,
                              void* d_out, int out_size, void* d_ws, size_t ws_size,
                              hipStream_t stream) {
    const float* x    = (const float*)d_in[0];
    const float* W    = (const float*)d_in[1];
    const float* b    = (const float*)d_in[2];
    const int*   eidx = (const int*)d_in[3];
    float*       out  = (float*)d_out;
    const int N = in_sizes[0] / DD;

    const size_t need = (size_t)N * HH * sizeof(ushort);
    if (ws_size >= need) {
        ushort* yb = (ushort*)d_ws;
        gemm_mfma<<<(N + TM - 1) / TM, 256, 0, stream>>>(x, W, yb, N);
        edge_mean<<<(N + 7) / 8, 256, 0, stream>>>(yb, b, eidx, out, N);
    } else {
        direct_conv<<<N, 128, 0, stream>>>(x, W, b, eidx, out, N);
    }
}